// Round 7
// baseline (205.960 us; speedup 1.0000x reference)
//
#include <hip/hip_runtime.h>

// TripletColbertLoss on MFMA: q (B,Q,D), p/n (B,K,D) fp32 -> scalar.
// loss = relu(0.2 + neg - pos), score = sum_{b,q} max_k q.d
// B=256 Q=256 K=512 D=128.
//
// R9: eliminate the stage phase from the wave instruction stream.
// R3/R4/R8 proved time (67.5us) invariant under 2x occupancy, 2x LDS
// traffic, 2x barrier domains -> per-tile cost = stage + read + MFMA SUMMED
// (phase-locked 2-phase schedule). This round:
//   - docs staged as RAW FP32 via __builtin_amdgcn_global_load_lds (async
//     DMA, no VALU, no regs; compiler never auto-emits it)
//   - bf16 hi/lo truncation split done IN-REGISTER at read time; fragment
//     read is 2x ds_read_b128 (32B fp32) = same LDS bytes as old bh+bl
//   - convert VALU overlaps MFMA (separate pipes, m114)
//   - linear LDS (gload_lds requires it) + rule-#21 both-sides XOR swizzle:
//     global source addr pre-swizzled byte^((row&7)<<4), ds_read applies
//     the same XOR -> full 8-slot coverage, b128 at conflict-free floor
//   - T3-minimal loop: issue STAGE(t+1) -> compute(t) -> one barrier
// Blocking: 256 thr, 4 waves x 32 q-rows, grid (256 b, 4 = pass*2+qhalf),
// 4 blocks/CU. 16x16x32 MFMA, 3-term split, fp64 reduction (all verified).

#define MARGIN   0.2f
#define Bn       256
#define Qn       256
#define Kn       512
#define Dn       128
#define TN       32            // docs per tile
#define NT       (Kn / TN)     // 16 tiles
#define NTHREADS 256
#define TILE_BYTES (TN * Dn * 4)   // 16384 B per doc tile (fp32)

typedef __attribute__((ext_vector_type(8))) short short8;
typedef __attribute__((ext_vector_type(4))) float f32x4;
typedef __attribute__((ext_vector_type(4))) unsigned int u32x4;

// Truncation split (A prologue): x = hi + lo, both bf16 by bit-truncation.
__device__ __forceinline__ void split_trunc(float x, unsigned short& hi, unsigned short& lo) {
    unsigned int u = __float_as_uint(x);
    hi = (unsigned short)(u >> 16);
    float l = x - __uint_as_float(u & 0xFFFF0000u);
    lo = (unsigned short)(__float_as_uint(l) >> 16);
}

// Async global->LDS DMA, 16 B per lane. LDS dest = uniform base + lane*16.
__device__ __forceinline__ void gload16(const void* g, void* l) {
    __builtin_amdgcn_global_load_lds(
        (const __attribute__((address_space(1))) unsigned int*)g,
        (__attribute__((address_space(3))) unsigned int*)l, 16, 0, 0);
}

// Issue DMA of doc tile T into Bs[BUFLIT] (literal). Global source address is
// pre-swizzled so that a linear LDS write + XOR'd read yields correct data.
// LDS linear layout: row (=doc) stride 512 B; lane covers byte lane*16 of the
// (w*4+i)-th KB. row = 2*(4w+i) + (lane>>5); inner = (lane&31)*16.
#define ISSUE_TILE(BUFLIT, T)                                                  \
    if ((T) < NT) {                                                            \
        const char* gt = (const char*)docb + (size_t)(T) * TILE_BYTES;         \
        _Pragma("unroll")                                                      \
        for (int i = 0; i < 4; ++i) {                                          \
            int row  = 2 * (w * 4 + i) + (lane >> 5);                          \
            int goff = row * 512 + (((lane & 31) * 16) ^ ((row & 7) << 4));    \
            gload16(gt + goff, (char*)&Bs[BUFLIT][0] + (w * 4 + i) * 1024);    \
        }                                                                      \
    }

// Convert 8 fp32 (two f32x4) -> bh (bf16-hi short8) + bl (bf16-lo short8).
#define CONV8(F0, F1, BH, BL)                                                  \
    short8 BH, BL;                                                             \
    {                                                                          \
        unsigned int u0 = __float_as_uint(F0[0]), u1 = __float_as_uint(F0[1]); \
        unsigned int u2 = __float_as_uint(F0[2]), u3 = __float_as_uint(F0[3]); \
        unsigned int u4 = __float_as_uint(F1[0]), u5 = __float_as_uint(F1[1]); \
        unsigned int u6 = __float_as_uint(F1[2]), u7 = __float_as_uint(F1[3]); \
        u32x4 hv, lv;                                                          \
        hv[0] = (u1 & 0xFFFF0000u) | (u0 >> 16);                               \
        hv[1] = (u3 & 0xFFFF0000u) | (u2 >> 16);                               \
        hv[2] = (u5 & 0xFFFF0000u) | (u4 >> 16);                               \
        hv[3] = (u7 & 0xFFFF0000u) | (u6 >> 16);                               \
        float l0 = F0[0] - __uint_as_float(u0 & 0xFFFF0000u);                  \
        float l1 = F0[1] - __uint_as_float(u1 & 0xFFFF0000u);                  \
        float l2 = F0[2] - __uint_as_float(u2 & 0xFFFF0000u);                  \
        float l3 = F0[3] - __uint_as_float(u3 & 0xFFFF0000u);                  \
        float l4 = F1[0] - __uint_as_float(u4 & 0xFFFF0000u);                  \
        float l5 = F1[1] - __uint_as_float(u5 & 0xFFFF0000u);                  \
        float l6 = F1[2] - __uint_as_float(u6 & 0xFFFF0000u);                  \
        float l7 = F1[3] - __uint_as_float(u7 & 0xFFFF0000u);                  \
        lv[0] = (__float_as_uint(l1) & 0xFFFF0000u) | (__float_as_uint(l0) >> 16); \
        lv[1] = (__float_as_uint(l3) & 0xFFFF0000u) | (__float_as_uint(l2) >> 16); \
        lv[2] = (__float_as_uint(l5) & 0xFFFF0000u) | (__float_as_uint(l4) >> 16); \
        lv[3] = (__float_as_uint(l7) & 0xFFFF0000u) | (__float_as_uint(l6) >> 16); \
        BH = __builtin_bit_cast(short8, hv);                                   \
        BL = __builtin_bit_cast(short8, lv);                                   \
    }

// One tile's compute from Bs[BUFLIT]: 2 ni x 4 ks x (2 ds_read_b128 ->
// in-reg convert -> 6 MFMAs over 2 independent chains), fold row-max.
#define COMPUTE_TILE(BUFLIT)                                                   \
    {                                                                          \
        const char* base = (const char*)&Bs[BUFLIT][0];                        \
        _Pragma("unroll")                                                      \
        for (int ni = 0; ni < 2; ++ni) {                                       \
            f32x4 a0 = (f32x4){0.f, 0.f, 0.f, 0.f};                            \
            f32x4 a1 = (f32x4){0.f, 0.f, 0.f, 0.f};                            \
            _Pragma("unroll")                                                  \
            for (int ks = 0; ks < 4; ++ks) {                                   \
                int r    = ni * 16 + l16;                                      \
                int swz  = (r & 7) << 4;                                       \
                int coff = ks * 128 + quad * 32;                               \
                f32x4 f0 = *(const f32x4*)(base + r * 512 + ((coff) ^ swz));   \
                f32x4 f1 = *(const f32x4*)(base + r * 512 + ((coff + 16) ^ swz)); \
                CONV8(f0, f1, bh, bl)                                          \
                a0 = __builtin_amdgcn_mfma_f32_16x16x32_bf16(Ahi[0][ks], bh, a0, 0, 0, 0); \
                a1 = __builtin_amdgcn_mfma_f32_16x16x32_bf16(Ahi[1][ks], bh, a1, 0, 0, 0); \
                a0 = __builtin_amdgcn_mfma_f32_16x16x32_bf16(Alo[0][ks], bh, a0, 0, 0, 0); \
                a1 = __builtin_amdgcn_mfma_f32_16x16x32_bf16(Alo[1][ks], bh, a1, 0, 0, 0); \
                a0 = __builtin_amdgcn_mfma_f32_16x16x32_bf16(Ahi[0][ks], bl, a0, 0, 0, 0); \
                a1 = __builtin_amdgcn_mfma_f32_16x16x32_bf16(Ahi[1][ks], bl, a1, 0, 0, 0); \
            }                                                                  \
            _Pragma("unroll")                                                  \
            for (int rr = 0; rr < 4; ++rr) {                                   \
                maxv[0][rr] = fmaxf(maxv[0][rr], a0[rr]);                      \
                maxv[1][rr] = fmaxf(maxv[1][rr], a1[rr]);                      \
            }                                                                  \
        }                                                                      \
    }

__global__ __launch_bounds__(NTHREADS, 4)
void colbert_pass_kernel(const float* __restrict__ qg,
                         const float* __restrict__ pg,
                         const float* __restrict__ ng,
                         double* __restrict__ sum_ws) {
    __shared__ float Bs[2][TN * Dn];        // [buf][doc*128 + dim] fp32, LINEAR (32 KB)
    __shared__ float part[4];

    const int tid  = threadIdx.x;
    const int w    = tid >> 6;              // 4 waves
    const int lane = tid & 63;
    const int l16  = lane & 15;
    const int quad = lane >> 4;
    const int b    = blockIdx.x;
    const int y    = blockIdx.y;
    const int pass = y >> 1;                // 0 -> p (+), 1 -> n (-)
    const int qh   = y & 1;                 // q-half: rows [qh*128, qh*128+128)

    const float* docb = (pass ? ng : pg) + (size_t)b * Kn * Dn;

    // Issue tile 0 DMA first: lands during the A-conversion VALU burst.
    ISSUE_TILE(0, 0)

    // ---- A fragments: 32 q-rows per wave (mi = 0,1 -> 16 rows each).
    // 16x16x32 A layout: lane holds A[m = l16][k = quad*8 + j], j=0..7.
    short8 Ahi[2][4], Alo[2][4];            // [mi][ks]
    {
        const float* qb = qg + (size_t)b * Qn * Dn;
#pragma unroll
        for (int mi = 0; mi < 2; ++mi)
#pragma unroll
            for (int ks = 0; ks < 4; ++ks) {
                const float* src = qb + (size_t)(qh * 128 + w * 32 + mi * 16 + l16) * Dn
                                      + ks * 32 + quad * 8;
                float4 v0 = *(const float4*)src;
                float4 v1 = *(const float4*)(src + 4);
                float x[8] = {v0.x, v0.y, v0.z, v0.w, v1.x, v1.y, v1.z, v1.w};
#pragma unroll
                for (int j = 0; j < 8; ++j) {
                    unsigned short h, l;
                    split_trunc(x[j], h, l);
                    Ahi[mi][ks][j] = (short)h;
                    Alo[mi][ks][j] = (short)l;
                }
            }
    }

    float maxv[2][4];                       // [mi][reg] running row-max
#pragma unroll
    for (int mi = 0; mi < 2; ++mi)
#pragma unroll
        for (int r = 0; r < 4; ++r) maxv[mi][r] = -3e38f;

    __syncthreads();                        // drains vmcnt -> tile 0 in LDS

    // Main loop, x2 unrolled for literal buffer indices (rule #20).
    // Body(t): issue DMA(t+1 -> buf^1) -> compute(buf) -> barrier.
    // The end-of-body __syncthreads drains vmcnt: DMA had the whole compute
    // phase (~4k cyc) to cover ~900 cyc HBM latency.
    for (int t = 0; t < NT; t += 2) {
        ISSUE_TILE(1, t + 1)                // t+1 <= 15 always
        COMPUTE_TILE(0)
        __syncthreads();
        ISSUE_TILE(0, t + 2)
        COMPUTE_TILE(1)
        __syncthreads();
    }

    // max over the 16 doc-column lanes
#pragma unroll
    for (int off = 1; off < 16; off <<= 1)
#pragma unroll
        for (int mi = 0; mi < 2; ++mi)
#pragma unroll
            for (int r = 0; r < 4; ++r)
                maxv[mi][r] = fmaxf(maxv[mi][r], __shfl_xor(maxv[mi][r], off));

    float s = 0.f;
#pragma unroll
    for (int mi = 0; mi < 2; ++mi)
#pragma unroll
        for (int r = 0; r < 4; ++r) s += maxv[mi][r];
    if (l16 != 0) s = 0.f;                  // one copy per quad
    s += __shfl_xor(s, 16);                 // combine the 4 quads
    s += __shfl_xor(s, 32);
    if (lane == 0) part[w] = s;
    __syncthreads();
    if (tid == 0) {
        double t = (double)part[0] + part[1] + part[2] + part[3];
        atomicAdd(sum_ws, pass ? -t : t);   // S = pos - neg, exact in fp64
    }
}

__global__ void finalize_kernel(const double* __restrict__ sum_ws,
                                float* __restrict__ out) {
    out[0] = fmaxf(0.0f, MARGIN - (float)sum_ws[0]);
}

extern "C" void kernel_launch(void* const* d_in, const int* in_sizes, int n_in,
                              void* d_out, int out_size, void* d_ws, size_t ws_size,
                              hipStream_t stream) {
    const float* q = (const float*)d_in[0];
    const float* p = (const float*)d_in[1];
    const float* n = (const float*)d_in[2];
    float* out = (float*)d_out;
    double* ws = (double*)d_ws;

    hipMemsetAsync(ws, 0, sizeof(double), stream);  // ws re-poisoned each call

    colbert_pass_kernel<<<dim3(Bn, 4), NTHREADS, 0, stream>>>(q, p, n, ws);
    finalize_kernel<<<1, 1, 0, stream>>>(ws, out);
}